// Round 2
// baseline (279.535 us; speedup 1.0000x reference)
//
#include <hip/hip_runtime.h>

// BindingFormer fused pipeline for MI355X (gfx950).
// Stages: frames -> node MLP (rep, bf16) -> weight fold/swizzle -> fused edge kernel (MFMA).
// Output written as FLOAT32 (reference returns f32; round-1 bf16 write gave the
// exact interleaved-pair error signature of an f32 readback).

typedef __attribute__((ext_vector_type(8))) short short8;  // 8 x bf16 (4 VGPRs)
typedef __attribute__((ext_vector_type(4))) float f32x4;   // MFMA accumulator

#define TWO_PI 6.283185307179586f
#define E_AB_TOT 131072
#define E_TOT    133120

// ws layout (bytes)
#define WS_RT    0         // frames: 1024 x 12 f32            = 49152
#define WS_WG1   49152     // composed geom weight 27x256 f32  = 27648
#define WS_REPB  76800     // rep bf16 1024x256                = 524288
#define WS_W1F   601088    // swizzled W1' 19*16*64*8 bf16     = 311296
#define WS_W2F   912384    // swizzled W2  8*8*64*8 bf16       = 65536
// total 977920 bytes

__device__ __forceinline__ unsigned short f2bf(float x){
  unsigned int u = __float_as_uint(x);
  u += 0x7fffu + ((u >> 16) & 1u);            // RTNE
  return (unsigned short)(u >> 16);
}

// jax.nn.gelu default = tanh approximation
__device__ __forceinline__ float gelu_t(float x){
  float z = 0.7978845608028654f * (x + 0.044715f * x * x * x);
  float e = __expf(2.0f * z);
  float t = 1.0f - 2.0f / (e + 1.0f);         // tanh(z), robust at +/-inf
  return 0.5f * x * (1.0f + t);
}

// ---------------- frames: R (columns e1,e2,e3) + t per node ----------------
__global__ void frames_k(const float* __restrict__ coords, float* __restrict__ RT){
  int n = blockIdx.x * blockDim.x + threadIdx.x;
  if (n >= 1024) return;
  const float* p = coords + n * 9;
  float ax=p[0],ay=p[1],az=p[2], bx=p[3],by=p[4],bz=p[5], cx=p[6],cy=p[7],cz=p[8];
  float v1x=cx-bx, v1y=cy-by, v1z=cz-bz;
  float v2x=ax-bx, v2y=ay-by, v2z=az-bz;
  float n1 = sqrtf(v1x*v1x+v1y*v1y+v1z*v1z) + 1e-6f;
  float e1x=v1x/n1, e1y=v1y/n1, e1z=v1z/n1;
  float dp = e1x*v2x + e1y*v2y + e1z*v2z;
  float u2x=v2x-e1x*dp, u2y=v2y-e1y*dp, u2z=v2z-e1z*dp;
  float n2 = sqrtf(u2x*u2x+u2y*u2y+u2z*u2z) + 1e-6f;
  float e2x=u2x/n2, e2y=u2y/n2, e2z=u2z/n2;
  float e3x = e1y*e2z - e1z*e2y;
  float e3y = e1z*e2x - e1x*e2z;
  float e3z = e1x*e2y - e1y*e2x;
  float* r = RT + n * 12;
  r[0]=e1x; r[1]=e2x; r[2]=e3x;   // r[i*3+k] = R[i][k] (i = coord axis, k = basis col)
  r[3]=e1y; r[4]=e2y; r[5]=e3y;
  r[6]=e1z; r[7]=e2z; r[8]=e3z;
  r[9]=bx;  r[10]=by; r[11]=bz;
}

// ---------------- node MLP: rep = gelu_mlp([emb, te]) + emb, store bf16 ----
__global__ __launch_bounds__(256) void rep_k(
    const float* __restrict__ emb, const float* __restrict__ ts,
    const float* __restrict__ tf,  const float* __restrict__ w1,
    const float* __restrict__ b1,  const float* __restrict__ w2,
    const float* __restrict__ b2,  unsigned short* __restrict__ repb){
  __shared__ float x[288];
  __shared__ float h[256];
  int n = blockIdx.x, t = threadIdx.x;
  x[t] = emb[n * 256 + t];
  if (t < 16){
    float ang = TWO_PI * ts[n] * tf[t];
    float s, c; __sincosf(ang, &s, &c);
    x[256 + t] = s; x[272 + t] = c;           // fourier: [sin(16), cos(16)]
  }
  __syncthreads();
  float acc = b1[t];
  for (int k = 0; k < 288; ++k) acc += x[k] * w1[k * 256 + t];
  h[t] = gelu_t(acc);
  __syncthreads();
  float acc2 = b2[t];
  for (int k = 0; k < 256; ++k) acc2 += h[k] * w2[k * 256 + t];
  acc2 += x[t];                                // residual
  repb[n * 256 + t] = f2bf(acc2);
}

// ---------------- Wg1 = w_geom (27x128) @ w1_edge[0:128] (128x256) ---------
__global__ __launch_bounds__(256) void wg1_k(
    const float* __restrict__ wg, const float* __restrict__ w1e, float* __restrict__ wg1){
  int r = blockIdx.x, t = threadIdx.x;
  float acc = 0.f;
  for (int j = 0; j < 128; ++j) acc += wg[r * 128 + j] * w1e[j * 256 + t];
  wg1[r * 256 + t] = acc;
}

// ---------------- swizzle W1' (608x256) into B-fragment order --------------
// K layout: [0:27 geom feats (Wg1) | 27:91 rope rows (w1e 128:192) | 91:96 zero
//            | 96:352 rep_src rows (w1e 192:448) | 352:608 rep_dst rows (w1e 448:704)]
// B-frag: lane holds B[k = (lane>>4)*8 + j][n = lane&15] within each 32-K step.
__global__ __launch_bounds__(64) void swz1_k(
    const float* __restrict__ wg1, const float* __restrict__ w1e, unsigned short* __restrict__ w1f){
  int s = blockIdx.x >> 4, c = blockIdx.x & 15;
  int lane = threadIdx.x;
  int n  = c * 16 + (lane & 15);
  int kb = s * 32 + (lane >> 4) * 8;
  unsigned short* o = w1f + (((s * 16 + c) * 64) + lane) * 8;
  for (int j = 0; j < 8; ++j){
    int k = kb + j;
    float val;
    if      (k < 27)  val = wg1[k * 256 + n];
    else if (k < 91)  val = w1e[(128 + k - 27)  * 256 + n];
    else if (k < 96)  val = 0.f;
    else if (k < 352) val = w1e[(192 + k - 96)  * 256 + n];
    else              val = w1e[(448 + k - 352) * 256 + n];
    o[j] = f2bf(val);
  }
}

__global__ __launch_bounds__(64) void swz2_k(
    const float* __restrict__ w2e, unsigned short* __restrict__ w2f){
  int s = blockIdx.x >> 3, c = blockIdx.x & 7;
  int lane = threadIdx.x;
  int n  = c * 16 + (lane & 15);
  int kb = s * 32 + (lane >> 4) * 8;
  unsigned short* o = w2f + (((s * 8 + c) * 64) + lane) * 8;
  for (int j = 0; j < 8; ++j)
    o[j] = f2bf(w2e[(kb + j) * 128 + n]);
}

// ---------------- fused edge kernel ----------------------------------------
// 64 edges/block, 512 threads (8 waves). LDS edge_in tile 64x608 bf16 (stride 616),
// GEMM1 K=608 -> gelu -> h (64x256, stride 264, aliased) -> GEMM2 K=256 -> f32 out.
__global__ __launch_bounds__(512, 4) void edge_k(
    const unsigned short* __restrict__ repb, const float* __restrict__ RT,
    const float* __restrict__ cf,
    const int* __restrict__ resi, const int* __restrict__ chain,
    const int* __restrict__ gia,  const int* __restrict__ gib,
    const int* __restrict__ pid,
    const unsigned short* __restrict__ w1f, const unsigned short* __restrict__ w2f,
    const float* __restrict__ b1, const float* __restrict__ b2,
    float* __restrict__ outp)
{
  __shared__ __align__(16) char smem[78848];   // 64 rows x 616 bf16
  __shared__ int lsrc[64];
  __shared__ int ldst[64];
  unsigned short* Erow = (unsigned short*)smem;

  int tid = threadIdx.x;
  int e0  = blockIdx.x * 64;

  if (tid < 64){
    int e = e0 + tid, s_, d_;
    if (e < E_AB_TOT){ s_ = gia[e]; d_ = gib[e]; }
    else {
      int i = e - E_AB_TOT;
      int b = i >> 10, w_ = i & 1023;
      s_ = pid[b * 32 + (w_ >> 5)];
      d_ = pid[b * 32 + (w_ & 31)];
    }
    lsrc[tid] = s_; ldst[tid] = d_;
  }
  __syncthreads();

  // gather rep rows: 64 edges x 2 rows x 512 B, coalesced 16 B/lane
  {
    const uint4* rep4 = (const uint4*)repb;    // 32 uint4 per 256-bf16 row
    #pragma unroll
    for (int i = 0; i < 8; ++i){
      int cid  = tid + 512 * i;
      int ed   = cid >> 6, part = (cid >> 5) & 1, off = cid & 31;
      int row  = part ? ldst[ed] : lsrc[ed];
      uint4 v  = rep4[row * 32 + off];
      *(uint4*)(smem + ed * 1232 + 192 + part * 512 + off * 16) = v;
    }
  }

  // per-edge scalar features -> cols 0:96
  if (tid < 64){
    int s_ = lsrc[tid], d_ = ldst[tid];
    unsigned short* row = Erow + tid * 616;
    float ris  = (float)resi[s_], ridd = (float)resi[d_];
    float disp = (ris - ridd) * 0.125f;
    float inv  = (chain[s_] == chain[d_]) ? 1.f / (fabsf(disp) + 1.f) : 0.f;
    for (int j = 0; j < 32; ++j){
      float ss, cc;
      __sincosf(TWO_PI * disp * cf[j], &ss, &cc);
      row[27 + j] = f2bf(ss * inv);
      row[59 + j] = f2bf(cc * inv);
    }
    for (int j = 91; j < 96; ++j) row[j] = 0;
    const float* Rs = RT + s_ * 12;
    const float* Rd = RT + d_ * 12;
    float dx = Rd[9]-Rs[9], dy = Rd[10]-Rs[10], dz = Rd[11]-Rs[11];
    float dist = sqrtf(dx*dx + dy*dy + dz*dz + 1e-6f);
    float invd = 1.f / (dist + 1.f);
    for (int j = 0; j < 15; ++j){               // rbf: centers linspace(0,20,15), sig=20/15
      float z = (dist - (float)j * (20.f / 14.f)) * (15.f / 20.f);
      row[j] = f2bf(__expf(-0.5f * z * z));
    }
    #pragma unroll
    for (int a = 0; a < 3; ++a)                 // relrot = R_src^T R_dst, a-major
      #pragma unroll
      for (int b_ = 0; b_ < 3; ++b_){
        float v = Rs[a]*Rd[b_] + Rs[3+a]*Rd[3+b_] + Rs[6+a]*Rd[6+b_];
        row[15 + a * 3 + b_] = f2bf(v);
      }
    #pragma unroll
    for (int k = 0; k < 3; ++k){                // local = R_src^T d / (dist+1)
      float v = Rs[k]*dx + Rs[3+k]*dy + Rs[6+k]*dz;
      row[24 + k] = f2bf(v * invd);
    }
  }
  __syncthreads();

  // ---- GEMM1: (64x608) x (608x256), 16x16x32 bf16 MFMA ----
  int w    = tid >> 6, lane = tid & 63;
  int rt   = w & 3;                 // rowtile (4 x 16 rows)
  int c0   = (w >> 2) * 8;          // 8 coltiles per wave (16 total)
  int mrow = rt * 16 + (lane & 15);
  int qoff = (lane >> 4) * 16;      // quad byte offset within 32-k step
  int quad = lane >> 4;
  f32x4 acc[8];
  #pragma unroll
  for (int c = 0; c < 8; ++c) acc[c] = (f32x4){0.f, 0.f, 0.f, 0.f};
  const short8* w1f8 = (const short8*)w1f;

  for (int s = 0; s < 19; ++s){
    short8 a = *(const short8*)(smem + mrow * 1232 + s * 64 + qoff);
    const short8* bp = w1f8 + (s * 16 + c0) * 64 + lane;
    #pragma unroll
    for (int c = 0; c < 8; ++c){
      short8 b = bp[c * 64];
      acc[c] = __builtin_amdgcn_mfma_f32_16x16x32_bf16(a, b, acc[c], 0, 0, 0);
    }
  }
  __syncthreads();   // all waves done reading edge_in; alias LDS as h

  // h = gelu(acc + b1) -> LDS (stride 264 bf16)
  unsigned short* H = (unsigned short*)smem;
  #pragma unroll
  for (int c = 0; c < 8; ++c){
    int n = (c0 + c) * 16 + (lane & 15);
    float bias = b1[n];
    #pragma unroll
    for (int r = 0; r < 4; ++r){
      int m = rt * 16 + quad * 4 + r;           // C/D: row = quad*4+reg, col = lane&15
      H[m * 264 + n] = f2bf(gelu_t(acc[c][r] + bias));
    }
  }
  __syncthreads();

  // ---- GEMM2: (64x256) x (256x128) ----
  int c20 = (w >> 2) * 4;
  f32x4 acc2[4];
  #pragma unroll
  for (int c = 0; c < 4; ++c) acc2[c] = (f32x4){0.f, 0.f, 0.f, 0.f};
  const short8* w2f8 = (const short8*)w2f;
  for (int s = 0; s < 8; ++s){
    short8 a = *(const short8*)(smem + mrow * 528 + s * 64 + qoff);
    #pragma unroll
    for (int c = 0; c < 4; ++c){
      short8 b = w2f8[(s * 8 + c20 + c) * 64 + lane];
      acc2[c] = __builtin_amdgcn_mfma_f32_16x16x32_bf16(a, b, acc2[c], 0, 0, 0);
    }
  }

  // f32 epilogue: direct register -> global (16 lanes x 4 B = 64 B segments)
  float* og = outp + (size_t)e0 * 128;
  #pragma unroll
  for (int c = 0; c < 4; ++c){
    int n = (c20 + c) * 16 + (lane & 15);
    float bias = b2[n];
    #pragma unroll
    for (int r = 0; r < 4; ++r){
      int m = rt * 16 + quad * 4 + r;
      og[m * 128 + n] = acc2[c][r] + bias;
    }
  }
}

extern "C" void kernel_launch(void* const* d_in, const int* in_sizes, int n_in,
                              void* d_out, int out_size, void* d_ws, size_t ws_size,
                              hipStream_t stream) {
  const float* emb    = (const float*)d_in[0];
  const float* ts     = (const float*)d_in[1];
  const float* coords = (const float*)d_in[2];
  const float* tf     = (const float*)d_in[3];
  const float* cf     = (const float*)d_in[4];
  const float* w1r    = (const float*)d_in[5];
  const float* b1r    = (const float*)d_in[6];
  const float* w2r    = (const float*)d_in[7];
  const float* b2r    = (const float*)d_in[8];
  const float* wg     = (const float*)d_in[9];
  const float* w1e    = (const float*)d_in[10];
  const float* b1e    = (const float*)d_in[11];
  const float* w2e    = (const float*)d_in[12];
  const float* b2e    = (const float*)d_in[13];
  const int* resi     = (const int*)d_in[14];
  const int* chain    = (const int*)d_in[15];
  const int* gia      = (const int*)d_in[16];
  const int* gib      = (const int*)d_in[17];
  const int* pid      = (const int*)d_in[18];

  char* ws = (char*)d_ws;
  float* RT            = (float*)(ws + WS_RT);
  float* WG1           = (float*)(ws + WS_WG1);
  unsigned short* REPB = (unsigned short*)(ws + WS_REPB);
  unsigned short* W1F  = (unsigned short*)(ws + WS_W1F);
  unsigned short* W2F  = (unsigned short*)(ws + WS_W2F);
  float* outp          = (float*)d_out;        // f32 output per reference dtype

  hipLaunchKernelGGL(frames_k, dim3(4),    dim3(256), 0, stream, coords, RT);
  hipLaunchKernelGGL(rep_k,    dim3(1024), dim3(256), 0, stream, emb, ts, tf, w1r, b1r, w2r, b2r, REPB);
  hipLaunchKernelGGL(wg1_k,    dim3(27),   dim3(256), 0, stream, wg, w1e, WG1);
  hipLaunchKernelGGL(swz1_k,   dim3(304),  dim3(64),  0, stream, WG1, w1e, W1F);
  hipLaunchKernelGGL(swz2_k,   dim3(64),   dim3(64),  0, stream, w2e, W2F);
  hipLaunchKernelGGL(edge_k,   dim3(2080), dim3(512), 0, stream,
                     REPB, RT, cf, resi, chain, gia, gib, pid, W1F, W2F, b1e, b2e, outp);
}